// Round 6
// baseline (131.345 us; speedup 1.0000x reference)
//
#include <hip/hip_runtime.h>

#define NROWS  16384
#define RPB    4           // rows (=waves) per block
#define DIM    2048
#define KSEL   64          // TOPK/2 per side
#define FACTOR 6.26f
#define CAP    96          // per-side tie-candidate capacity (mean ~35, sigma ~6)
#define TPB    256

// Monotone order-preserving float->uint transform:
// ascending x  <=>  ascending u ; all negatives < all positives.
__device__ __forceinline__ unsigned f2ord(float f) {
    unsigned b = __float_as_uint(f);
    unsigned m = ((unsigned)((int)b >> 31)) | 0x80000000u;
    return b ^ m;
}

// Intra-wave LDS fence: DS ops complete in-order per wave; drain own queue.
// sched_barrier stops hipcc hoisting dependent ops past the asm (rule #18).
#define WFENCE() do { \
    __asm__ volatile("s_waitcnt lgkmcnt(0)" ::: "memory"); \
    __builtin_amdgcn_sched_barrier(0); \
} while (0)

__global__ __launch_bounds__(TPB, 6)
void kcomp_kernel(const float* __restrict__ xin, float* __restrict__ out)
{
    // All LDS is per-wave private -> no __syncthreads anywhere.
    __shared__ unsigned histS[RPB][1024];     // 2048 u16 bins packed in pairs, XOR-swizzled
    __shared__ uint4    candS[RPB][2][CAP/4]; // packed (keyLow21<<11)|(2047-idx)
    __shared__ unsigned wbitsS[RPB][2][64];   // tie-winner bitmap (2048 bits/side)
    __shared__ int      cntS[RPB][2];
    __shared__ int      shdS[RPB][8];         // P: D,need,eqc @0..2 ; N: @4..6

    const int tid  = threadIdx.x;
    const int lane = tid & 63;
    const int wid  = tid >> 6;

    unsigned* hist  = histS[wid];
    unsigned* candP = (unsigned*)candS[wid][0];
    unsigned* candN = (unsigned*)candS[wid][1];
    unsigned* wbP   = wbitsS[wid][0];
    unsigned* wbN   = wbitsS[wid][1];
    int*      cnt   = cntS[wid];
    int*      shd   = shdS[wid];

    const int row = blockIdx.x * RPB + wid;
    const size_t rowbase = (size_t)row * DIM;
    const float4* pin = (const float4*)(xin + rowbase);

    // ---- clear per-wave LDS (conflict-free strides) ----
    #pragma unroll
    for (int t = 0; t < 16; ++t) hist[lane + 64 * t] = 0u;
    ((unsigned*)wbitsS[wid])[lane]      = 0u;
    ((unsigned*)wbitsS[wid])[lane + 64] = 0u;
    if (lane < 2) cnt[lane] = 0;

    // ---- load + transform; lane owns elements {256q + 4*lane + r} ----
    unsigned u[32];
    #pragma unroll
    for (int q = 0; q < 8; ++q) {
        float4 v = pin[64 * q + lane];
        u[4*q+0] = f2ord(v.x); u[4*q+1] = f2ord(v.y);
        u[4*q+2] = f2ord(v.z); u[4*q+3] = f2ord(v.w);
    }
    WFENCE();   // clears complete before atomics

    // ---- histogram: 11-bit digit (u>>21), swizzled packed-u16 bins ----
    #pragma unroll
    for (int e = 0; e < 32; ++e) {
        unsigned d  = u[e] >> 21;
        unsigned w  = d >> 1;
        unsigned sw = w ^ ((w >> 5) & 31u);
        atomicAdd(&hist[sw], 1u << ((d & 1u) << 4));
    }
    WFENCE();   // histogram complete

    // ---- scan: lane owns bins [32L,32L+32) = words [16L,16L+16) (de-swizzled) ----
    unsigned hw[16];
    {
        const unsigned g = ((unsigned)lane >> 1) & 31u;
        #pragma unroll
        for (int r = 0; r < 16; ++r)
            hw[r] = hist[(unsigned)(16 * lane + r) ^ g];
    }
    unsigned S = 0;
    #pragma unroll
    for (int r = 0; r < 16; ++r) S += hw[r];
    const unsigned L = (S & 0xffffu) + (S >> 16);   // halves can't carry (<=2048)
    unsigned sc = L;
    #pragma unroll
    for (int off = 1; off < 64; off <<= 1) {
        unsigned v = __shfl_up(sc, off);
        if (lane >= off) sc += v;
    }
    const unsigned base = sc - L;

    // ---- crossing walk: only the straddling lane(s) ----
    {
        const unsigned TN = KSEL;               // bottom-64 crossing
        const unsigned TP = DIM - KSEL + 1;     // top-64 crossing (1985)
        const unsigned hiB = base + L;
        if ((base < TN && TN <= hiB) || (base < TP && TP <= hiB)) {
            unsigned acc = base;
            #pragma unroll
            for (int i = 0; i < 32; ++i) {
                unsigned h = (i & 1) ? (hw[i >> 1] >> 16) : (hw[i >> 1] & 0xffffu);
                unsigned acc2 = acc + h;
                if (acc < TN && TN <= acc2) { shd[4] = 32*lane + i; shd[5] = (int)(TN - acc);          shd[6] = (int)h; }
                if (acc < TP && TP <= acc2) { shd[0] = 32*lane + i; shd[1] = (int)(acc2 - (TP - 1));   shd[2] = (int)h; }
                acc = acc2;
            }
        }
    }
    WFENCE();   // crossing published

    const int Dp = shd[0], needP = shd[1], eqcP = shd[2];
    const int Dn = shd[4], needN = shd[5], eqcN = shd[6];
    const bool fastP = (eqcP == needP);
    const bool fastN = (eqcN == needN);
    const unsigned tieLoP = (unsigned)Dp << 21;
    const unsigned tieLoN = (unsigned)Dn << 21;
    unsigned long long h64 = ((unsigned long long)(Dp + 1)) << 21;
    const unsigned hiP = (h64 > 0xFFFFFFFFull) ? 0xFFFFFFFFu : (unsigned)h64;
    h64 = ((unsigned long long)(Dn + 1)) << 21;
    const unsigned hiN = (h64 > 0xFFFFFFFFull) ? 0xFFFFFFFFu : (unsigned)h64;
    const unsigned thrP = fastP ? tieLoP : hiP;      // plain winners: u >= thrP
    const unsigned thrN = fastN ? hiN    : tieLoN;   // plain winners: u <  thrN
    const unsigned tieLenP = fastP ? 0u : 0x200000u;
    const unsigned tieLenN = fastN ? 0u : 0x200000u;

    // ---- gather tie candidates (packed keys unique -> exact lowest-index tie-break) ----
    #pragma unroll
    for (int e = 0; e < 32; ++e) {
        const unsigned idx = (unsigned)(256 * (e >> 2) + 4 * lane + (e & 3));
        if (u[e] - tieLoP < tieLenP) {
            int s = atomicAdd(&cnt[0], 1);
            if (s < CAP) candP[s] = ((u[e] & 0x1FFFFFu) << 11) | (2047u - idx);
        }
        if (u[e] - tieLoN < tieLenN) {
            int s = atomicAdd(&cnt[1], 1);
            if (s < CAP) candN[s] = (((~u[e]) & 0x1FFFFFu) << 11) | (2047u - idx);
        }
    }
    WFENCE();   // candidates + counts visible

    const int ecP = min(cnt[0], CAP);
    const int ecN = min(cnt[1], CAP);

    // ---- rank ties; winners (rank < need) set bits in the bitmap ----
    if (!fastP) {
        for (int j = lane; j < ecP; j += 64) {
            const unsigned mine = candP[j];
            int rank = 0;
            const int nt = (ecP + 3) >> 2;
            for (int t = 0; t < nt; ++t) {
                uint4 c = candS[wid][0][t];          // broadcast read
                int s = 4 * t;
                rank += (c.x > mine);
                rank += ((s + 1 < ecP) && (c.y > mine));
                rank += ((s + 2 < ecP) && (c.z > mine));
                rank += ((s + 3 < ecP) && (c.w > mine));
            }
            if (rank < needP) {
                unsigned idx = 2047u - (mine & 2047u);
                atomicOr(&wbP[idx >> 5], 1u << (idx & 31u));
            }
        }
    }
    if (!fastN) {
        for (int j = lane; j < ecN; j += 64) {
            const unsigned mine = candN[j];
            int rank = 0;
            const int nt = (ecN + 3) >> 2;
            for (int t = 0; t < nt; ++t) {
                uint4 c = candS[wid][1][t];
                int s = 4 * t;
                rank += (c.x > mine);
                rank += ((s + 1 < ecN) && (c.y > mine));
                rank += ((s + 2 < ecN) && (c.z > mine));
                rank += ((s + 3 < ecN) && (c.w > mine));
            }
            if (rank < needN) {
                unsigned idx = 2047u - (mine & 2047u);
                atomicOr(&wbN[idx >> 5], 1u << (idx & 31u));
            }
        }
    }
    WFENCE();   // bitmaps final

    // ---- assemble this lane's 32 tie-winner bits (nibble per q) ----
    unsigned mP = 0, mN = 0;
    {
        const int wbase = lane >> 3;
        const int nsh = 4 * (lane & 7);
        #pragma unroll
        for (int q = 0; q < 8; ++q) {
            mP |= ((wbP[8 * q + wbase] >> nsh) & 15u) << (4 * q);
            mN |= ((wbN[8 * q + wbase] >> nsh) & 15u) << (4 * q);
        }
    }

    // ---- classify + loser energy (px/nx derived bitwise from u) ----
    float lp = 0.f, ln = 0.f;
    unsigned fullP = 0, fullN = 0;
    #pragma unroll
    for (int e = 0; e < 32; ++e) {
        const bool wP = (u[e] >= thrP) || ((mP >> e) & 1u);
        const bool wN = (u[e] <  thrN) || ((mN >> e) & 1u);
        if (wP) fullP |= 1u << e;
        if (wN) fullN |= 1u << e;
        const bool pos = u[e] >= 0x80000000u;
        const float px = pos ? __uint_as_float(u[e] ^ 0x80000000u) : 0.f;
        const float nx = pos ? 0.f : __uint_as_float((~u[e]) & 0x7FFFFFFFu);
        if (!wP) lp += px;
        if (!wN) ln += nx;
    }
    #pragma unroll
    for (int d = 1; d < 64; d <<= 1) {      // butterfly: all lanes get totals
        lp += __shfl_xor(lp, d);
        ln += __shfl_xor(ln, d);
    }
    const float Ptmp = FACTOR * lp;
    const float Ntmp = FACTOR * ln;

    // ---- output ----
    float4* pout = (float4*)(out + rowbase);
    #pragma unroll
    for (int q = 0; q < 8; ++q) {
        float4 o;
        #pragma unroll
        for (int r = 0; r < 4; ++r) {
            const int e = 4 * q + r;
            const bool pos = u[e] >= 0x80000000u;
            const float px = pos ? __uint_as_float(u[e] ^ 0x80000000u) : 0.f;
            const float nx = pos ? 0.f : __uint_as_float((~u[e]) & 0x7FFFFFFFu);
            float v = ((fullP >> e) & 1u) ? (px + Ptmp) : 0.f;
            v -= ((fullN >> e) & 1u) ? (nx + Ntmp) : 0.f;
            (&o.x)[r] = v;
        }
        pout[64 * q + lane] = o;
    }
}

extern "C" void kernel_launch(void* const* d_in, const int* in_sizes, int n_in,
                              void* d_out, int out_size, void* d_ws, size_t ws_size,
                              hipStream_t stream)
{
    const float* x = (const float*)d_in[0];
    float* out = (float*)d_out;
    (void)in_sizes; (void)n_in; (void)d_ws; (void)ws_size; (void)out_size;
    kcomp_kernel<<<NROWS / RPB, TPB, 0, stream>>>(x, out);
}

// Round 7
// 92.872 us; speedup vs baseline: 1.4143x; 1.4143x over previous
//
#include <hip/hip_runtime.h>

#define NROWS  16384
#define DIM    2048
#define KSEL   64          // TOPK/2 per side
#define FACTOR 6.26f
#define CAP    96          // per-side tie-candidate capacity (tie bin mean ~35)
#define TPB    256

// Monotone order-preserving float->uint transform:
// ascending x  <=>  ascending u ; all negatives < all positives.
__device__ __forceinline__ unsigned f2ord(float f) {
    unsigned b = __float_as_uint(f);
    unsigned m = ((unsigned)((int)b >> 31)) | 0x80000000u;
    return b ^ m;
}

__device__ __forceinline__ int      rfl (int v)      { return __builtin_amdgcn_readfirstlane(v); }
__device__ __forceinline__ unsigned rflu(unsigned v) { return (unsigned)__builtin_amdgcn_readfirstlane((int)v); }
__device__ __forceinline__ float    rflf(float v)    { return __uint_as_float(rflu(__float_as_uint(v))); }

__global__ __launch_bounds__(TPB)
void kcomp_kernel(const float* __restrict__ xin, float* __restrict__ out)
{
    __shared__ unsigned hist32[1024];     // 2048 u16 bins packed in pairs (4 KB)
    __shared__ uint4    cand4[2][CAP/4];  // packed (keyLow21<<11)|(2047-idx), pre-zeroed
    __shared__ int      cnt[2];
    __shared__ int      shd[8];           // P: D,need,eqc,cut @0..3 ; N: @4..7
    __shared__ float    redf[8];

    const int tid  = threadIdx.x;
    const int lane = tid & 63;
    const int wid  = tid >> 6;
    const size_t rowbase = (size_t)blockIdx.x * DIM;
    const float4* pin = (const float4*)(xin + rowbase);

    // thread t owns consecutive elements [8t, 8t+8)
    float4 va = pin[2 * tid];
    float4 vb = pin[2 * tid + 1];
    float xv[8] = {va.x, va.y, va.z, va.w, vb.x, vb.y, vb.z, vb.w};
    unsigned u[8];
    #pragma unroll
    for (int e = 0; e < 8; ++e) u[e] = f2ord(xv[e]);

    // ---- clear: hist (4 KB) + cand (768 B, rank-pad zeros) + cnt + shd ----
    ((uint4*)hist32)[tid] = (uint4){0u, 0u, 0u, 0u};
    if (tid < 2 * CAP / 4) ((uint4*)cand4)[tid] = (uint4){0u, 0u, 0u, 0u};
    if (tid < 2) cnt[tid] = 0;
    if (tid < 8) shd[tid] = 0;
    __syncthreads();                                   // B1

    // ---- single histogram pass: 11-bit digit (u>>21), serves BOTH sides ----
    #pragma unroll
    for (int e = 0; e < 8; ++e) {
        unsigned d = u[e] >> 21;
        atomicAdd(&hist32[d >> 1], 1u << ((d & 1u) << 4));
    }
    __syncthreads();                                   // B2

    // ---- wave 0 scans the entire histogram (32 bins/lane) + crossing walk ----
    if (wid == 0) {
        uint4 h0 = ((const uint4*)hist32)[4 * lane + 0];
        uint4 h1 = ((const uint4*)hist32)[4 * lane + 1];
        uint4 h2 = ((const uint4*)hist32)[4 * lane + 2];
        uint4 h3 = ((const uint4*)hist32)[4 * lane + 3];
        unsigned S = h0.x + h0.y + h0.z + h0.w + h1.x + h1.y + h1.z + h1.w
                   + h2.x + h2.y + h2.z + h2.w + h3.x + h3.y + h3.z + h3.w;
        unsigned L = (S & 0xffffu) + (S >> 16);        // halves can't carry (<=2048)
        unsigned sc = L;
        #pragma unroll
        for (int off = 1; off < 64; off <<= 1) {
            unsigned v = __shfl_up(sc, off);
            if (lane >= off) sc += v;
        }
        const unsigned base = sc - L;
        const unsigned TN = KSEL;                      // bottom-64 crossing
        const unsigned TP = DIM - KSEL + 1;            // top-64 crossing (1985)
        if ((base < TN && TN <= sc) || (base < TP && TP <= sc)) {
            unsigned w[16] = {h0.x, h0.y, h0.z, h0.w, h1.x, h1.y, h1.z, h1.w,
                              h2.x, h2.y, h2.z, h2.w, h3.x, h3.y, h3.z, h3.w};
            unsigned acc = base;
            #pragma unroll
            for (int i = 0; i < 32; ++i) {
                unsigned h = (i & 1) ? (w[i >> 1] >> 16) : (w[i >> 1] & 0xffffu);
                unsigned a2 = acc + h;
                if (acc < TN && TN <= a2) { shd[4] = 32 * lane + i; shd[5] = (int)(TN - acc);        shd[6] = (int)h; }
                if (acc < TP && TP <= a2) { shd[0] = 32 * lane + i; shd[1] = (int)(a2 - (TP - 1));   shd[2] = (int)h; }
                acc = a2;
            }
        }
    }
    __syncthreads();                                   // B3

    // ---- block-uniform selection parameters -> SGPRs ----
    const int Dp = rfl(shd[0]), needP = rfl(shd[1]), eqcP = rfl(shd[2]);
    const int Dn = rfl(shd[4]), needN = rfl(shd[5]), eqcN = rfl(shd[6]);
    const bool fastP = (eqcP == needP);                // all tie-bin members win
    const bool fastN = (eqcN == needN);
    const unsigned tieLoP = (unsigned)Dp << 21;
    const unsigned tieLoN = (unsigned)Dn << 21;
    const unsigned hiP = (Dp == 2047) ? 0xFFFFFFFFu : ((unsigned)(Dp + 1) << 21);
    const unsigned hiN = (Dn == 2047) ? 0xFFFFFFFFu : ((unsigned)(Dn + 1) << 21);
    const unsigned thrP = fastP ? tieLoP : hiP;        // plain winners: u >= thrP
    const unsigned thrN = fastN ? hiN    : tieLoN;     // plain winners: u <  thrN
    const unsigned tieLenP = fastP ? 0u : 0x200000u;
    const unsigned tieLenN = fastN ? 0u : 0x200000u;

    // ---- gather tie candidates (packed keys unique -> exact lowest-index tie-break) ----
    #pragma unroll
    for (int e = 0; e < 8; ++e) {
        const unsigned idx = (unsigned)((tid << 3) | e);
        if (u[e] - tieLoP < tieLenP) {
            int s = atomicAdd(&cnt[0], 1);
            if (s < CAP) ((unsigned*)cand4[0])[s] = ((u[e] & 0x1FFFFFu) << 11) | (2047u - idx);
        }
        if (u[e] - tieLoN < tieLenN) {
            int s = atomicAdd(&cnt[1], 1);
            if (s < CAP) ((unsigned*)cand4[1])[s] = (((~u[e]) & 0x1FFFFFu) << 11) | (2047u - idx);
        }
    }
    __syncthreads();                                   // B4

    // ---- rank: wave0 -> P, wave1 -> N; publish the need-th largest as cut ----
    // cand tail is pre-zeroed; pad key 0 never out-ranks a real key.
    if (wid < 2) {
        const int side = wid;
        const bool fast = side ? fastN : fastP;
        if (!fast) {
            const int need = side ? needN : needP;
            const int ec   = min(rfl(cnt[side]), CAP);
            const int nt   = (ec + 3) >> 2;
            for (int j = lane; j < ec; j += 64) {
                const unsigned mine = ((const unsigned*)cand4[side])[j];
                int rank = 0;
                for (int t = 0; t < nt; ++t) {
                    uint4 c = cand4[side][t];          // broadcast LDS read
                    rank += (c.x > mine) + (c.y > mine) + (c.z > mine) + (c.w > mine);
                }
                if (rank == need - 1) shd[side ? 7 : 3] = (int)mine;
            }
        }
    }
    __syncthreads();                                   // B5
    const unsigned cutP = rflu((unsigned)shd[3]);
    const unsigned cutN = rflu((unsigned)shd[7]);

    // ---- classify + loser energy (fused) ----
    unsigned winP = 0, winN = 0;
    float lp = 0.f, ln = 0.f;
    #pragma unroll
    for (int e = 0; e < 8; ++e) {
        const unsigned idx = (unsigned)((tid << 3) | e);
        bool wP = (u[e] >= thrP);
        bool wN = (u[e] <  thrN);
        if (u[e] - tieLoP < tieLenP) {
            unsigned pk = ((u[e] & 0x1FFFFFu) << 11) | (2047u - idx);
            wP |= (pk >= cutP);
        }
        if (u[e] - tieLoN < tieLenN) {
            unsigned pk = (((~u[e]) & 0x1FFFFFu) << 11) | (2047u - idx);
            wN |= (pk >= cutN);
        }
        winP |= (unsigned)wP << e;
        winN |= (unsigned)wN << e;
        const float px = fmaxf(xv[e], 0.f);
        if (!wP) lp += px;
        if (!wN) ln += px - xv[e];                     // px - x == fmaxf(-x,0)
    }
    #pragma unroll
    for (int off = 32; off; off >>= 1) {
        lp += __shfl_down(lp, off);
        ln += __shfl_down(ln, off);
    }
    if (lane == 0) { redf[wid] = lp; redf[4 + wid] = ln; }
    __syncthreads();                                   // B6
    const float Ptmp = rflf(FACTOR * (redf[0] + redf[1] + redf[2] + redf[3]));
    const float Ntmp = rflf(FACTOR * (redf[4] + redf[5] + redf[6] + redf[7]));

    // ---- output ----
    float4 o0, o1;
    #pragma unroll
    for (int e = 0; e < 8; ++e) {
        const float px = fmaxf(xv[e], 0.f);
        const float nx = px - xv[e];
        float v = ((winP >> e) & 1u) ? (px + Ptmp) : 0.f;
        v -= ((winN >> e) & 1u) ? (nx + Ntmp) : 0.f;
        ((e < 4) ? (&o0.x) : (&o1.x))[e & 3] = v;
    }
    float4* pout = (float4*)(out + rowbase);
    pout[2 * tid]     = o0;
    pout[2 * tid + 1] = o1;
}

extern "C" void kernel_launch(void* const* d_in, const int* in_sizes, int n_in,
                              void* d_out, int out_size, void* d_ws, size_t ws_size,
                              hipStream_t stream)
{
    const float* x = (const float*)d_in[0];
    float* out = (float*)d_out;
    (void)in_sizes; (void)n_in; (void)d_ws; (void)ws_size; (void)out_size;
    kcomp_kernel<<<NROWS, TPB, 0, stream>>>(x, out);
}

// Round 8
// 86.897 us; speedup vs baseline: 1.5115x; 1.0688x over previous
//
#include <hip/hip_runtime.h>

#define NROWS  16384
#define RPB    4           // rows (= independent waves) per 256-thread block
#define DIM    2048
#define KSEL   64          // TOPK/2 per side
#define FACTOR 6.26f
#define CAP    96          // per-side tie-candidate capacity (tie bin mean ~35, 10 sigma)
#define TPB    256

// Monotone order-preserving float->uint transform:
// ascending x  <=>  ascending u ; all negatives < all positives.
__device__ __forceinline__ unsigned f2ord(float f) {
    unsigned b = __float_as_uint(f);
    unsigned m = ((unsigned)((int)b >> 31)) | 0x80000000u;
    return b ^ m;
}

__device__ __forceinline__ int rfl(int v) { return __builtin_amdgcn_readfirstlane(v); }

// Intra-wave LDS fence: drain own DS queue; sched_barrier stops hoisting (rule #18).
#define WFENCE() do { \
    __asm__ volatile("s_waitcnt lgkmcnt(0)" ::: "memory"); \
    __builtin_amdgcn_sched_barrier(0); \
} while (0)

__global__ __launch_bounds__(TPB, 4)   // 128-VGPR cap: room for u[32]+temps, no spills
void kcomp_kernel(const float* __restrict__ xin, float* __restrict__ out)
{
    // All LDS per-wave private -> zero __syncthreads in the whole kernel.
    __shared__ unsigned histS[RPB][1024];     // 2048 u16 bins packed in pairs (4 KB/wave)
    __shared__ uint4    candS[RPB][2][CAP/4]; // packed (keyLow21<<11)|(2047-idx), tail stays 0
    __shared__ int      cntS[RPB][2];
    __shared__ int      shdS[RPB][8];         // P: bin,need,eqc,cut @0..3 ; N: @4..7

    const int lane = threadIdx.x & 63;
    const int wid  = threadIdx.x >> 6;
    unsigned* hist  = histS[wid];
    unsigned* candP = (unsigned*)candS[wid][0];
    unsigned* candN = (unsigned*)candS[wid][1];
    int*      cnt   = cntS[wid];
    int*      shd   = shdS[wid];

    const int row = blockIdx.x * RPB + wid;
    const size_t rowbase = (size_t)row * DIM;
    const float4* pin = (const float4*)(xin + rowbase);

    // ---- clear per-wave LDS ----
    #pragma unroll
    for (int t = 0; t < 16; ++t) hist[lane + 64 * t] = 0u;
    {
        unsigned* c = (unsigned*)candS[wid];          // 192 words
        c[lane] = 0u; c[lane + 64] = 0u; c[lane + 128] = 0u;
    }
    if (lane < 2) cnt[lane] = 0;
    if (lane < 8) shd[lane] = 0;

    // ---- load + transform: lane owns elements idx = 256q + 4*lane + r ----
    unsigned u[32];
    #pragma unroll
    for (int q = 0; q < 8; ++q) {
        float4 v = pin[64 * q + lane];
        u[4*q+0] = f2ord(v.x); u[4*q+1] = f2ord(v.y);
        u[4*q+2] = f2ord(v.z); u[4*q+3] = f2ord(v.w);
    }
    WFENCE();   // clears drained before atomics

    // ---- histogram: 11-bit digit (u>>21), packed u16 pairs ----
    #pragma unroll
    for (int e = 0; e < 32; ++e) {
        unsigned d = u[e] >> 21;
        atomicAdd(&hist[d >> 1], 1u << ((d & 1u) << 4));
    }
    WFENCE();   // histogram complete (own wave only)

    // ---- scan: lane owns bins [32L,32L+32) = words [16L,16L+16) ----
    unsigned S = 0;
    {
        const uint4* h4 = (const uint4*)hist;
        #pragma unroll
        for (int t = 0; t < 4; ++t) {
            uint4 h = h4[4 * lane + t];
            S += h.x + h.y + h.z + h.w;               // halves can't carry (<=2048)
        }
    }
    const unsigned L = (S & 0xffffu) + (S >> 16);
    unsigned sc = L;
    #pragma unroll
    for (int off = 1; off < 64; off <<= 1) {
        unsigned v = __shfl_up(sc, off);
        if (lane >= off) sc += v;
    }
    const unsigned base = sc - L;

    // ---- crossing walk: only straddling lane(s) re-read their words ----
    {
        const unsigned TN = KSEL;                     // bottom-64 crossing
        const unsigned TP = DIM - KSEL + 1;           // top-64 crossing (1985)
        if ((base < TN && TN <= sc) || (base < TP && TP <= sc)) {
            const uint4* h4 = (const uint4*)hist;
            unsigned acc = base;
            for (int t = 0; t < 4; ++t) {
                uint4 h = h4[4 * lane + t];
                unsigned w[4] = {h.x, h.y, h.z, h.w};
                #pragma unroll
                for (int k = 0; k < 8; ++k) {
                    unsigned hv = (k & 1) ? (w[k >> 1] >> 16) : (w[k >> 1] & 0xffffu);
                    unsigned a2 = acc + hv;
                    int bin = 32 * lane + 8 * t + k;
                    if (acc < TN && TN <= a2) { shd[4] = bin; shd[5] = (int)(TN - acc);        shd[6] = (int)hv; }
                    if (acc < TP && TP <= a2) { shd[0] = bin; shd[1] = (int)(a2 - (TP - 1));   shd[2] = (int)hv; }
                    acc = a2;
                }
            }
        }
    }
    WFENCE();   // crossing published

    const int Dp = rfl(shd[0]), needP = rfl(shd[1]), eqcP = rfl(shd[2]);
    const int Dn = rfl(shd[4]), needN = rfl(shd[5]), eqcN = rfl(shd[6]);
    const bool fastP = (eqcP == needP);               // whole tie bin wins
    const bool fastN = (eqcN == needN);
    const unsigned tieLoP = (unsigned)Dp << 21;
    const unsigned tieLoN = (unsigned)Dn << 21;
    const unsigned tieLenP = fastP ? 0u : 0x200000u;
    const unsigned tieLenN = fastN ? 0u : 0x200000u;

    // ---- gather tie candidates (sparse: ~35/2048 elements) ----
    #pragma unroll
    for (int e = 0; e < 32; ++e) {
        const unsigned idx = 256u * (e >> 2) + 4u * (unsigned)lane + (e & 3);
        if (u[e] - tieLoP < tieLenP) {
            int s = atomicAdd(&cnt[0], 1);
            if (s < CAP) candP[s] = ((u[e] & 0x1FFFFFu) << 11) | (2047u - idx);
        }
        if (u[e] - tieLoN < tieLenN) {
            int s = atomicAdd(&cnt[1], 1);
            if (s < CAP) candN[s] = (((~u[e]) & 0x1FFFFFu) << 11) | (2047u - idx);
        }
    }
    WFENCE();   // candidates + counts visible

    // ---- rank ties (whole wave, P then N); publish the need-th largest key ----
    // cand tail pre-zeroed: pad key 0 never out-ranks a real key; ranks are a
    // permutation (keys unique), so exactly one lane publishes.
    if (!fastP) {
        const int ec = min(rfl(cnt[0]), CAP);
        const int nt = (ec + 3) >> 2;
        for (int j = lane; j < ec; j += 64) {
            const unsigned mine = candP[j];
            int rank = 0;
            for (int t = 0; t < nt; ++t) {
                uint4 c = candS[wid][0][t];           // broadcast LDS read
                rank += (c.x > mine) + (c.y > mine) + (c.z > mine) + (c.w > mine);
            }
            if (rank == needP - 1) shd[3] = (int)mine;
        }
    }
    if (!fastN) {
        const int ec = min(rfl(cnt[1]), CAP);
        const int nt = (ec + 3) >> 2;
        for (int j = lane; j < ec; j += 64) {
            const unsigned mine = candN[j];
            int rank = 0;
            for (int t = 0; t < nt; ++t) {
                uint4 c = candS[wid][1][t];
                rank += (c.x > mine) + (c.y > mine) + (c.z > mine) + (c.w > mine);
            }
            if (rank == needN - 1) shd[7] = (int)mine;
        }
    }
    WFENCE();   // cuts published

    // ---- exact unified cut: winner iff u>uCut || (u==uCut && idx<=idxCut) ----
    unsigned uCutP, uCutN; int idxCutP, idxCutN;
    if (fastP) { uCutP = tieLoP; idxCutP = 2047; }
    else {
        const unsigned c = (unsigned)rfl(shd[3]);
        uCutP = tieLoP | (c >> 11); idxCutP = 2047 - (int)(c & 2047u);
    }
    if (fastN) { uCutN = tieLoN | 0x1FFFFFu; idxCutN = 2047; }
    else {
        const unsigned c = (unsigned)rfl(shd[7]);
        uCutN = tieLoN | ((~(c >> 11)) & 0x1FFFFFu); idxCutN = 2047 - (int)(c & 2047u);
    }

    // ---- classify + loser energy ----
    const int relP = idxCutP - 4 * lane;              // idx<=idxCut  <=>  Ce <= rel
    const int relN = idxCutN - 4 * lane;
    unsigned fullP = 0, fullN = 0;
    float lp = 0.f, ln = 0.f;
    #pragma unroll
    for (int e = 0; e < 32; ++e) {
        const int Ce = 256 * (e >> 2) + (e & 3);
        const bool wP = (u[e] > uCutP) || ((u[e] == uCutP) && (Ce <= relP));
        const bool wN = (u[e] < uCutN) || ((u[e] == uCutN) && (Ce <= relN));
        fullP |= (unsigned)wP << e;
        fullN |= (unsigned)wN << e;
        const bool pos = (u[e] >= 0x80000000u);
        const float px = pos ? __uint_as_float(u[e] ^ 0x80000000u) : 0.f;
        const float nx = pos ? 0.f : __uint_as_float((~u[e]) & 0x7FFFFFFFu);
        if (!wP) lp += px;
        if (!wN) ln += nx;
    }
    #pragma unroll
    for (int d = 1; d < 64; d <<= 1) {                // butterfly: all lanes get totals
        lp += __shfl_xor(lp, d);
        ln += __shfl_xor(ln, d);
    }
    const float Ptmp = FACTOR * lp;
    const float Ntmp = FACTOR * ln;

    // ---- output ----
    float4* pout = (float4*)(out + rowbase);
    #pragma unroll
    for (int q = 0; q < 8; ++q) {
        float4 o;
        #pragma unroll
        for (int r = 0; r < 4; ++r) {
            const int e = 4 * q + r;
            const bool pos = (u[e] >= 0x80000000u);
            const float px = pos ? __uint_as_float(u[e] ^ 0x80000000u) : 0.f;
            const float nx = pos ? 0.f : __uint_as_float((~u[e]) & 0x7FFFFFFFu);
            float v = ((fullP >> e) & 1u) ? (px + Ptmp) : 0.f;
            v -= ((fullN >> e) & 1u) ? (nx + Ntmp) : 0.f;
            (&o.x)[r] = v;
        }
        pout[64 * q + lane] = o;
    }
}

extern "C" void kernel_launch(void* const* d_in, const int* in_sizes, int n_in,
                              void* d_out, int out_size, void* d_ws, size_t ws_size,
                              hipStream_t stream)
{
    const float* x = (const float*)d_in[0];
    float* out = (float*)d_out;
    (void)in_sizes; (void)n_in; (void)d_ws; (void)ws_size; (void)out_size;
    kcomp_kernel<<<NROWS / RPB, TPB, 0, stream>>>(x, out);
}